// Round 1
// baseline (467.035 us; speedup 1.0000x reference)
//
#include <hip/hip_runtime.h>

// SimpleLSTM: 2-layer LSTM (B=512,T=256,F=64,U=128) + Dense(1,relu).
// Persistent-RNN design: fp16 weights pinned in VGPRs (per-wave column slice),
// h_t through double-buffered LDS, 1 barrier/step, fp32 accum/state.
// 256 WGs x 512 threads; each WG = 2 batch rows (M=16 MFMA, padded).
// log2e folded into weights => sigmoid/tanh are exp2+rcp only.

#define T_STEPS 256
#define BATCH   512
#define NU      128
#define FDIM    64

typedef _Float16 h8 __attribute__((ext_vector_type(8)));
typedef _Float16 h4 __attribute__((ext_vector_type(4)));
typedef float    f4 __attribute__((ext_vector_type(4)));

#define LOG2E    1.4426950408889634f
#define TWOLOG2E 2.8853900817779268f

#if __has_builtin(__builtin_amdgcn_exp2f)
#define EXP2F(x) __builtin_amdgcn_exp2f(x)
#else
#define EXP2F(x) exp2f(x)
#endif
#if __has_builtin(__builtin_amdgcn_rcpf)
#define RCPF(x) __builtin_amdgcn_rcpf(x)
#else
#define RCPF(x) (1.0f / (x))
#endif

// s = z*log2e  -> sigmoid(z)
__device__ __forceinline__ float sigm2(float s) {
    return RCPF(1.0f + EXP2F(-s));
}
// t = 2*z*log2e -> tanh(z)
__device__ __forceinline__ float tanh2(float t) {
    return 1.0f - 2.0f * RCPF(1.0f + EXP2F(t));
}

// ---- weight prep: transpose to col-major [col][k], cast fp16, fold log2e ----
__global__ void prep_weights(const float* __restrict__ W1, const float* __restrict__ U1,
                             const float* __restrict__ b1, const float* __restrict__ W2,
                             const float* __restrict__ U2, const float* __restrict__ b2,
                             _Float16* __restrict__ Wp1, _Float16* __restrict__ Up1,
                             _Float16* __restrict__ Wp2, _Float16* __restrict__ Up2,
                             float* __restrict__ bp1, float* __restrict__ bp2) {
    int i = blockIdx.x * 256 + threadIdx.x;
    if (i < 32768) {                       // Wp1 [512][64] from W1 [64][512]
        int col = i >> 6, k = i & 63;
        float sc = ((col >> 7) == 2) ? TWOLOG2E : LOG2E;
        Wp1[i] = (_Float16)(W1[k * 512 + col] * sc);
    } else if (i < 32768 + 65536) {        // Up1 [512][128] from U1 [128][512]
        int j = i - 32768; int col = j >> 7, k = j & 127;
        float sc = ((col >> 7) == 2) ? TWOLOG2E : LOG2E;
        Up1[j] = (_Float16)(U1[k * 512 + col] * sc);
    } else if (i < 32768 + 131072) {       // Wp2 [512][128] from W2 [128][512]
        int j = i - 98304; int col = j >> 7, k = j & 127;
        float sc = ((col >> 7) == 2) ? TWOLOG2E : LOG2E;
        Wp2[j] = (_Float16)(W2[k * 512 + col] * sc);
    } else if (i < 32768 + 196608) {       // Up2 [512][128] from U2 [128][512]
        int j = i - 163840; int col = j >> 7, k = j & 127;
        float sc = ((col >> 7) == 2) ? TWOLOG2E : LOG2E;
        Up2[j] = (_Float16)(U2[k * 512 + col] * sc);
    } else if (i < 32768 + 196608 + 1024) {
        int j = i - 229376;
        if (j < 512) {
            float sc = ((j >> 7) == 2) ? TWOLOG2E : LOG2E;
            bp1[j] = b1[j] * sc;
        } else {
            int col = j - 512;
            float sc = ((col >> 7) == 2) ? TWOLOG2E : LOG2E;
            bp2[col] = b2[col] * sc;
        }
    }
}

// ---- LSTM layer kernel ----
// IS_A: input = x (f32 [B,T,F]), writes hs fp16 [T,B,U].
// !IS_A: input = hs (fp16 [T,B,U]), fused dense at end.
template <bool IS_A>
__global__ __launch_bounds__(512) void lstm_layer(
    const float* __restrict__ xA, const _Float16* __restrict__ xB,
    const _Float16* __restrict__ Wp,   // [512][KX] col-major, scaled fp16
    const _Float16* __restrict__ Up,   // [512][128]
    const float* __restrict__ bp,      // [512] scaled
    _Float16* __restrict__ hs_out,     // layer A output
    const float* __restrict__ Wd, const float* __restrict__ bd,
    float* __restrict__ dout) {
    constexpr int KX  = IS_A ? 64 : 128;
    constexpr int KXS = KX / 32;
    constexpr int PX  = IS_A ? 72 : 136;   // pitches chosen: 16B-aligned rows, bank-uniform b128 reads
    constexpr int PH  = 136;
    constexpr int XBUF = 16 * PX;
    constexpr int HBUF = 16 * PH;
    constexpr int SM   = 2 * XBUF + 2 * HBUF;
    __shared__ _Float16 sm[SM];

    const int tid  = threadIdx.x;
    const int lane = tid & 63;
    const int wv   = tid >> 6;       // 0..7, each owns 16 units
    const int m    = lane & 15;
    const int kc   = lane >> 4;      // quad 0..3
    const int u0   = wv * 16;
    const int b0   = blockIdx.x * 2;

    // zero LDS (pad rows 2..15 must stay zero forever)
    for (int i = tid; i < SM; i += 512) sm[i] = (_Float16)0.0f;

    // weight fragments -> registers (B-frag: B[k=kc*8+j][n=lane&15], col-major source)
    h8 wf[4][KXS], uf[4][4];
#pragma unroll
    for (int g = 0; g < 4; g++) {
#pragma unroll
        for (int ks = 0; ks < KXS; ks++)
            wf[g][ks] = *(const h8*)&Wp[(g * 128 + u0 + m) * KX + ks * 32 + kc * 8];
#pragma unroll
        for (int ks = 0; ks < 4; ks++)
            uf[g][ks] = *(const h8*)&Up[(g * 128 + u0 + m) * 128 + ks * 32 + kc * 8];
    }
    float bias[4];
#pragma unroll
    for (int g = 0; g < 4; g++) bias[g] = bp[g * 128 + u0 + m];

    const int prow = lane >> 4;   // staging row (lanes 0..31)
    const int pcol = lane & 15;

    __syncthreads();   // LDS zeroed

    // stage t=0 input into xbuf0
    if (wv == 0 && lane < 32) {
        if constexpr (IS_A) {
            f4 v = *(const f4*)&xA[(size_t)((b0 + prow) * T_STEPS + 0) * FDIM + pcol * 4];
            h4 hv = {(_Float16)v.x, (_Float16)v.y, (_Float16)v.z, (_Float16)v.w};
            *(h4*)&sm[prow * PX + pcol * 4] = hv;
        } else {
            *(h8*)&sm[prow * PX + pcol * 8] =
                *(const h8*)&xB[(size_t)(0 * BATCH + b0 + prow) * NU + pcol * 8];
        }
    }
    __syncthreads();

    float c0 = 0.0f, c1 = 0.0f;

    for (int t = 0; t < T_STEPS; t++) {
        const int p = t & 1;
        const _Float16* xb  = &sm[p * XBUF];
        const _Float16* hb  = &sm[2 * XBUF + p * HBUF];
        _Float16* xbn = &sm[(p ^ 1) * XBUF];
        _Float16* hbn = &sm[2 * XBUF + (p ^ 1) * HBUF];

        // prefetch next step's input (consumed after the epilogue)
        f4 xr; h8 xr8;
        const bool pf = (wv == 0) && (lane < 32) && (t + 1 < T_STEPS);
        if (pf) {
            if constexpr (IS_A)
                xr = *(const f4*)&xA[(size_t)((b0 + prow) * T_STEPS + (t + 1)) * FDIM + pcol * 4];
            else
                xr8 = *(const h8*)&xB[(size_t)((t + 1) * BATCH + b0 + prow) * NU + pcol * 8];
        }

        // A fragments from LDS: A[m=lane&15][k=kc*8+j]
        h8 xa[KXS], ha[4];
#pragma unroll
        for (int ks = 0; ks < KXS; ks++)
            xa[ks] = *(const h8*)&xb[m * PX + ks * 32 + kc * 8];
#pragma unroll
        for (int ks = 0; ks < 4; ks++)
            ha[ks] = *(const h8*)&hb[m * PH + ks * 32 + kc * 8];

        f4 acc[4];
#pragma unroll
        for (int g = 0; g < 4; g++) acc[g] = (f4){0.f, 0.f, 0.f, 0.f};
#pragma unroll
        for (int ks = 0; ks < KXS; ks++)
#pragma unroll
            for (int g = 0; g < 4; g++)
                acc[g] = __builtin_amdgcn_mfma_f32_16x16x32_f16(xa[ks], wf[g][ks], acc[g], 0, 0, 0);
#pragma unroll
        for (int ks = 0; ks < 4; ks++)
#pragma unroll
            for (int g = 0; g < 4; g++)
                acc[g] = __builtin_amdgcn_mfma_f32_16x16x32_f16(ha[ks], uf[g][ks], acc[g], 0, 0, 0);

        // gate epilogue on acc regs 0,1 only (real rows 0,1 live in lanes 0..15)
        float hv[2];
#pragma unroll
        for (int r = 0; r < 2; r++) {
            float zi = acc[0][r] + bias[0];
            float zf = acc[1][r] + bias[1];
            float zg = acc[2][r] + bias[2];
            float zo = acc[3][r] + bias[3];
            float gi = sigm2(zi), gf = sigm2(zf), go = sigm2(zo);
            float gg = tanh2(zg);
            float& cc = r ? c1 : c0;
            cc = gf * cc + gi * gg;
            hv[r] = go * tanh2(cc * TWOLOG2E);
        }
        _Float16 h0 = (_Float16)hv[0], h1 = (_Float16)hv[1];

        if (lane < 16) {   // col = lane&15 = unit u0+lane within this wave's slice
            hbn[0 * PH + u0 + m] = h0;
            hbn[1 * PH + u0 + m] = h1;
            if constexpr (IS_A) {
                hs_out[((size_t)t * BATCH + b0    ) * NU + u0 + m] = h0;
                hs_out[((size_t)t * BATCH + b0 + 1) * NU + u0 + m] = h1;
            }
        }
        if (pf) {
            if constexpr (IS_A) {
                h4 hv4 = {(_Float16)xr.x, (_Float16)xr.y, (_Float16)xr.z, (_Float16)xr.w};
                *(h4*)&xbn[prow * PX + pcol * 4] = hv4;
            } else {
                *(h8*)&xbn[prow * PX + pcol * 8] = xr8;
            }
        }
        __syncthreads();   // write(next) -> read(next) at t+1; also orders reuse of cur
    }

    if constexpr (!IS_A) {
        // h_{255} was written into hbuf[0] (t=255: p=1, writes p^1=0)
        const _Float16* hb = &sm[2 * XBUF + 0 * HBUF];
        if (wv == 0) {
            int row = lane >> 5, u = lane & 31;
            float s = 0.0f;
#pragma unroll
            for (int j = 0; j < 4; j++) {
                int uu = u + j * 32;
                s += (float)hb[row * PH + uu] * Wd[uu];
            }
            s += __shfl_xor(s, 16);
            s += __shfl_xor(s, 8);
            s += __shfl_xor(s, 4);
            s += __shfl_xor(s, 2);
            s += __shfl_xor(s, 1);
            if ((lane & 31) == 0) dout[b0 + row] = fmaxf(s + bd[0], 0.0f);
        }
    }
}

extern "C" void kernel_launch(void* const* d_in, const int* in_sizes, int n_in,
                              void* d_out, int out_size, void* d_ws, size_t ws_size,
                              hipStream_t stream) {
    const float* x  = (const float*)d_in[0];
    const float* W1 = (const float*)d_in[1];
    const float* U1 = (const float*)d_in[2];
    const float* b1 = (const float*)d_in[3];
    const float* W2 = (const float*)d_in[4];
    const float* U2 = (const float*)d_in[5];
    const float* b2 = (const float*)d_in[6];
    const float* Wd = (const float*)d_in[7];
    const float* bd = (const float*)d_in[8];
    float* out = (float*)d_out;

    // workspace layout (bytes)
    const size_t HS   = 33554432;              // hs fp16 [256][512][128]
    const size_t oWp1 = HS;                    // 65536
    const size_t oUp1 = oWp1 + 65536;          // 131072
    const size_t oWp2 = oUp1 + 131072;         // 131072
    const size_t oUp2 = oWp2 + 131072;         // 131072
    const size_t oBp1 = oUp2 + 131072;         // 2048
    const size_t oBp2 = oBp1 + 2048;           // 2048
    const size_t need = oBp2 + 2048;           // 34,017,280
    if (ws_size < need) return;                // clean fail rather than corruption

    char* ws = (char*)d_ws;
    _Float16* hs  = (_Float16*)ws;
    _Float16* Wp1 = (_Float16*)(ws + oWp1);
    _Float16* Up1 = (_Float16*)(ws + oUp1);
    _Float16* Wp2 = (_Float16*)(ws + oWp2);
    _Float16* Up2 = (_Float16*)(ws + oUp2);
    float*    bp1 = (float*)(ws + oBp1);
    float*    bp2 = (float*)(ws + oBp2);

    prep_weights<<<900, 256, 0, stream>>>(W1, U1, b1, W2, U2, b2,
                                          Wp1, Up1, Wp2, Up2, bp1, bp2);
    lstm_layer<true><<<256, 512, 0, stream>>>(x, nullptr, Wp1, Up1, bp1,
                                              hs, nullptr, nullptr, nullptr);
    lstm_layer<false><<<256, 512, 0, stream>>>(nullptr, hs, Wp2, Up2, bp2,
                                               nullptr, Wd, bd, out);
}